// Round 23
// baseline (238.169 us; speedup 1.0000x reference)
//
#include <hip/hip_runtime.h>

typedef __bf16 bf16;
typedef __attribute__((ext_vector_type(4))) __bf16 bf16x4;
typedef __attribute__((ext_vector_type(8))) __bf16 bf16x8;
typedef __attribute__((ext_vector_type(4))) float f32x4;

#define MFMA16(a, b, c) __builtin_amdgcn_mfma_f32_16x16x32_bf16((a), (b), (c), 0, 0, 0)

constexpr int N   = 8192;
constexpr int HID = 64;

// Block = 4 waves, SAME 16 output rows, K split 4 ways; per-wave pipeline,
// no in-loop barriers, LDS reduction at the end. A 4-deep NONTEMPORAL loads
// (R22: +16us — read-once stream must not allocate), B 4-deep caching loads
// (reused operand).
template <int EPI>
__global__ __launch_bounds__(256) void gcn_pass(const float* __restrict__ A, int K,
                                                const bf16* __restrict__ Bt,
                                                bf16* __restrict__ outT,
                                                const bf16* __restrict__ W23T,
                                                float* __restrict__ mu,
                                                float* __restrict__ lv) {
  __shared__ bf16  As[4][2][16 * 64];   // per-wave A staging (16 KB)
  __shared__ float Hred[4][16][68];     // per-wave partial C (17.4 KB)
  __shared__ float Ht[16][72];          // reduced C tile (4.6 KB)
  const int tid = threadIdx.x, lane = tid & 63, w = tid >> 6;
  const int r = lane & 15, hi = lane >> 4;
  const int i0 = blockIdx.x * 16;
  const int Kw = K >> 2;                // per-wave K slice
  const int kb0 = w * Kw;
  const int nt = Kw / 64;
  const int aR = hi;                    // A-load row within 4-row group
  const int aC = r * 4;                 // A-load f32 col (16B chunk)

  f32x4 ra[4][4];                       // 4-deep A tile rotation (64 VGPR)
  bf16x8 rb[4][8];                      // 4-deep B fragment sets (128 VGPR)
  f32x4 acc[4] = {};

  auto loadA = [&](f32x4 (&dst)[4], int t) {
    const int k0 = kb0 + t * 64;
#pragma unroll
    for (int s = 0; s < 4; ++s)
      dst[s] = __builtin_nontemporal_load(
          reinterpret_cast<const f32x4*>(&A[(size_t)(i0 + 4 * s + aR) * K + k0 + aC]));
  };
  auto loadB = [&](bf16x8 (&dst)[8], int t) {
    const int k0 = kb0 + t * 64;
#pragma unroll
    for (int n = 0; n < 4; ++n)
#pragma unroll
      for (int kk = 0; kk < 2; ++kk)
        dst[n * 2 + kk] = *reinterpret_cast<const bf16x8*>(
            &Bt[(size_t)(n * 16 + r) * K + k0 + kk * 32 + hi * 8]);
  };
  auto writeA = [&](int buf, const f32x4 (&src)[4]) {
    char* base = (char*)&As[w][buf][0];
#pragma unroll
    for (int s = 0; s < 4; ++s) {
      const int R = 4 * s + aR;
      bf16x4 o;
      o[0] = (bf16)src[s][0]; o[1] = (bf16)src[s][1];
      o[2] = (bf16)src[s][2]; o[3] = (bf16)src[s][3];
      *reinterpret_cast<bf16x4*>(base + R * 128 + ((aC * 2) ^ ((R & 7) << 4))) = o;
    }
  };
  auto compute = [&](int buf, const bf16x8 (&rbv)[8]) {
    const char* base = (const char*)&As[w][buf][0];
#pragma unroll
    for (int kk = 0; kk < 2; ++kk) {
      const bf16x8 fa = *reinterpret_cast<const bf16x8*>(
          base + r * 128 + ((kk * 64 + hi * 16) ^ ((r & 7) << 4)));
#pragma unroll
      for (int n = 0; n < 4; ++n)
        acc[n] = MFMA16(fa, rbv[n * 2 + kk], acc[n]);
    }
  };

  // prologue: A tiles 0..3 in regs, B tiles 0..2 in regs, A(0) into LDS buf0
  loadA(ra[0], 0);
  if (nt > 1) loadA(ra[1], 1);
  if (nt > 2) loadA(ra[2], 2);
  if (nt > 3) loadA(ra[3], 3);
  loadB(rb[0], 0);
  if (nt > 1) loadB(rb[1], 1);
  if (nt > 2) loadB(rb[2], 2);
  writeA(0, ra[0]);

  for (int tb = 0; tb < nt; tb += 4) {   // all slot indices compile-time
#pragma unroll
    for (int u = 0; u < 4; ++u) {
      const int t = tb + u;
      if (t >= nt) continue;
      if (t + 3 < nt) loadB(rb[(u + 3) & 3], t + 3);   // B 3 ahead
      if (t + 4 < nt) loadA(ra[u & 3], t + 4);         // A 4 ahead
      if (t + 1 < nt) writeA((u + 1) & 1, ra[(u + 1) & 3]);
      compute(u & 1, rb[u & 3]);
    }
  }

  // ---- cross-wave K-reduction + epilogue ----
  // C/D layout (m89-verified): col = lane&15, row = (lane>>4)*4 + reg
#pragma unroll
  for (int n = 0; n < 4; ++n)
#pragma unroll
    for (int g = 0; g < 4; ++g)
      Hred[w][hi * 4 + g][n * 16 + r] = acc[n][g];
  __syncthreads();
  {
    const int row = tid >> 4, c4 = (tid & 15) * 4;
    float4 s = {0.f, 0.f, 0.f, 0.f};
#pragma unroll
    for (int q = 0; q < 4; ++q) {
      const float4 v = *reinterpret_cast<const float4*>(&Hred[q][row][c4]);
      s.x += v.x; s.y += v.y; s.z += v.z; s.w += v.w;
    }
    if (EPI == 1) {
      s.x = fmaxf(s.x, 0.f); s.y = fmaxf(s.y, 0.f);
      s.z = fmaxf(s.z, 0.f); s.w = fmaxf(s.w, 0.f);
    }
    *reinterpret_cast<float4*>(&Ht[row][c4]) = s;
  }
  __syncthreads();

  if constexpr (EPI <= 1) {
    // transpose-store: outT[j][i0..i0+16], 256 threads (CACHING store: re-read
    // as next pass's B operand)
    const int j = tid >> 2, iq = tid & 3;
    bf16x4 o;
#pragma unroll
    for (int e = 0; e < 4; ++e) o[e] = (bf16)Ht[iq * 4 + e][j];
    *reinterpret_cast<bf16x4*>(&outT[(size_t)j * N + i0 + iq * 4]) = o;
  } else {
    // second MFMA: [16][128] = Ht(16x64) @ W23; wave w does q-blocks 2w,2w+1
    f32x4 a2[2] = {};
#pragma unroll
    for (int kk = 0; kk < 2; ++kk) {
      const float4 t0 = *reinterpret_cast<const float4*>(&Ht[r][kk * 32 + hi * 8]);
      const float4 t1 = *reinterpret_cast<const float4*>(&Ht[r][kk * 32 + hi * 8 + 4]);
      bf16x8 fa;
      fa[0] = (bf16)t0.x; fa[1] = (bf16)t0.y; fa[2] = (bf16)t0.z; fa[3] = (bf16)t0.w;
      fa[4] = (bf16)t1.x; fa[5] = (bf16)t1.y; fa[6] = (bf16)t1.z; fa[7] = (bf16)t1.w;
#pragma unroll
      for (int j = 0; j < 2; ++j) {
        const int q = w * 2 + j;
        const bf16x8 fw = *reinterpret_cast<const bf16x8*>(
            &W23T[(size_t)(q * 16 + r) * 64 + kk * 32 + hi * 8]);
        a2[j] = MFMA16(fa, fw, a2[j]);
      }
    }
#pragma unroll
    for (int j = 0; j < 2; ++j) {
      const int q = w * 2 + j;
      float* dst = (q < 4) ? mu : lv;
      const int cc = (q & 3) * 16 + r;
#pragma unroll
      for (int g = 0; g < 4; ++g)
        dst[(size_t)(i0 + hi * 4 + g) * HID + cc] = a2[j][g];
    }
  }
}

// W1 -> W1T [64][256] bf16 ; W2,W3 -> W23T [128][64] bf16 (single dispatch)
__global__ void prep_weights(const float* __restrict__ W1, const float* __restrict__ W2,
                             const float* __restrict__ W3, bf16* __restrict__ W1T,
                             bf16* __restrict__ W23T) {
  const int idx = blockIdx.x * 256 + threadIdx.x;  // 96 blocks = 24576
  if (idx < 16384) {
    const int j = idx >> 8, k = idx & 255;
    W1T[idx] = (bf16)W1[k * HID + j];
  } else {
    const int g = idx - 16384;                      // 8192
    const int j = g >> 6, c = g & 63;
    W23T[g] = (bf16)(j < 64 ? W2[c * HID + j] : W3[c * HID + (j - 64)]);
  }
}

// recon[i][j] = dot(mu[i,:], mu[j,:]) ; K=64, write-bound.
// NEW: NONTEMPORAL output stores — the 268MB write stream is never re-read;
// no-allocate keeps it from flushing L2/L3 for nothing.
constexpr int LDT = 72;
__global__ __launch_bounds__(256) void recon_mm(const float* __restrict__ mu,
                                                float* __restrict__ out) {
  __shared__ alignas(16) char pool[128 * LDT * 2 * 2];  // 36864 B: Am|Bm, then Ct
  bf16* Am = (bf16*)pool;                                // [128][72]
  bf16* Bm = (bf16*)(pool + 128 * LDT * 2);              // [128][72]
  float* Ct = (float*)pool;                              // [64][132] = 33792 B
  const int tid = threadIdx.x, lane = tid & 63, wave = tid >> 6;
  const int i0 = blockIdx.x * 128, j0 = blockIdx.y * 128;
  {
    const int rr = tid >> 4, c4 = tid & 15;
#pragma unroll
    for (int s = 0; s < 8; ++s) {
      const int row = rr + s * 16;
      const float4 v = *reinterpret_cast<const float4*>(&mu[(size_t)(i0 + row) * HID + c4 * 4]);
      bf16x4 o;
      o[0] = (bf16)v.x; o[1] = (bf16)v.y; o[2] = (bf16)v.z; o[3] = (bf16)v.w;
      *reinterpret_cast<bf16x4*>(&Am[row * LDT + c4 * 4]) = o;
      const float4 u = *reinterpret_cast<const float4*>(&mu[(size_t)(j0 + row) * HID + c4 * 4]);
      bf16x4 p;
      p[0] = (bf16)u.x; p[1] = (bf16)u.y; p[2] = (bf16)u.z; p[3] = (bf16)u.w;
      *reinterpret_cast<bf16x4*>(&Bm[row * LDT + c4 * 4]) = p;
    }
  }
  __syncthreads();
  f32x4 acc[2][8] = {};
  const int rA = wave * 32 + (lane & 15);
#pragma unroll
  for (int kk = 0; kk < 2; ++kk) {
    const int kb = kk * 32 + ((lane >> 4) << 3);
    const bf16x8 a0 = *reinterpret_cast<const bf16x8*>(&Am[rA * LDT + kb]);
    const bf16x8 a1 = *reinterpret_cast<const bf16x8*>(&Am[(rA + 16) * LDT + kb]);
#pragma unroll
    for (int n = 0; n < 8; ++n) {
      const bf16x8 b = *reinterpret_cast<const bf16x8*>(&Bm[(n * 16 + (lane & 15)) * LDT + kb]);
      acc[0][n] = MFMA16(a0, b, acc[0][n]);
      acc[1][n] = MFMA16(a1, b, acc[1][n]);
    }
  }
  const int r4 = (lane >> 4) << 2, c = lane & 15;
#pragma unroll
  for (int h = 0; h < 2; ++h) {
    __syncthreads();
    if ((wave >> 1) == h) {
      const int rbase = (wave & 1) * 32;
#pragma unroll
      for (int m = 0; m < 2; ++m)
#pragma unroll
        for (int n = 0; n < 8; ++n)
#pragma unroll
          for (int g = 0; g < 4; ++g)
            Ct[(rbase + m * 16 + r4 + g) * 132 + n * 16 + c] = acc[m][n][g];
    }
    __syncthreads();
#pragma unroll
    for (int s = 0; s < 8; ++s) {
      const int idx = tid + s * 256;       // 2048 float4 chunks
      const int row = idx >> 5, q = idx & 31;
      const f32x4 v = *reinterpret_cast<const f32x4*>(&Ct[row * 132 + q * 4]);
      __builtin_nontemporal_store(
          v, reinterpret_cast<f32x4*>(&out[(size_t)(i0 + h * 64 + row) * N + j0 + q * 4]));
    }
  }
}

extern "C" void kernel_launch(void* const* d_in, const int* in_sizes, int n_in, void* d_out,
                              int out_size, void* d_ws, size_t ws_size, hipStream_t stream) {
  const float* x   = (const float*)d_in[0];
  const float* adj = (const float*)d_in[1];
  const float* W1  = (const float*)d_in[2];
  const float* W2  = (const float*)d_in[3];
  const float* W3  = (const float*)d_in[4];

  float* out    = (float*)d_out;
  float* recon  = out;                          // [8192][8192] 256 MiB
  float* mu_out = out + (size_t)N * N;          // outside recon region
  float* lv_out = mu_out + (size_t)N * HID;

  // Scratch inside recon region (first ~3 MiB); all dead before recon_mm runs.
  char* scr   = (char*)d_out;
  bf16* S1T   = (bf16*)(scr + 0);               // [64][8192]  1 MB
  bf16* h1T   = (bf16*)(scr + (1u << 20));      // [64][8192]  1 MB
  bf16* W1T   = (bf16*)(scr + (2u << 20));      // [64][256]   32 KB
  bf16* W23T  = (bf16*)(scr + (2u << 20) + 65536);  // [128][64] 16 KB

  prep_weights<<<96, 256, 0, stream>>>(W1, W2, W3, W1T, W23T);
  // S1T = (x @ W1)^T
  gcn_pass<0><<<512, 256, 0, stream>>>(x, 256, W1T, S1T, nullptr, nullptr, nullptr);
  // h1T = relu(adj @ s1)^T   (nontemporal A-stream)
  gcn_pass<1><<<512, 256, 0, stream>>>(adj, N, S1T, h1T, nullptr, nullptr, nullptr);
  // mu, lv = (adj @ h1) @ {W2,W3}
  gcn_pass<2><<<512, 256, 0, stream>>>(adj, N, h1T, nullptr, W23T, mu_out, lv_out);
  // recon = mu @ mu^T  (nontemporal output stores)
  recon_mm<<<dim3(64, 64), 256, 0, stream>>>(mu_out, recon);
}

// Round 24
// 223.249 us; speedup vs baseline: 1.0668x; 1.0668x over previous
//
#include <hip/hip_runtime.h>

typedef __bf16 bf16;
typedef __attribute__((ext_vector_type(4))) __bf16 bf16x4;
typedef __attribute__((ext_vector_type(8))) __bf16 bf16x8;
typedef __attribute__((ext_vector_type(4))) float f32x4;

#define MFMA16(a, b, c) __builtin_amdgcn_mfma_f32_16x16x32_bf16((a), (b), (c), 0, 0, 0)

constexpr int N   = 8192;
constexpr int HID = 64;

// Block = 4 waves, SAME 16 output rows, K split 4 ways; per-wave pipeline,
// no in-loop barriers, LDS reduction at the end. A 4-deep NONTEMPORAL loads
// (R22: +16us — read-once stream must not allocate), B 4-deep caching loads
// (reused operand). Stores stay CACHING (R23: nt stores regressed −14us).
template <int EPI>
__global__ __launch_bounds__(256) void gcn_pass(const float* __restrict__ A, int K,
                                                const bf16* __restrict__ Bt,
                                                bf16* __restrict__ outT,
                                                const bf16* __restrict__ W23T,
                                                float* __restrict__ mu,
                                                float* __restrict__ lv) {
  __shared__ bf16  As[4][2][16 * 64];   // per-wave A staging (16 KB)
  __shared__ float Hred[4][16][68];     // per-wave partial C (17.4 KB)
  __shared__ float Ht[16][72];          // reduced C tile (4.6 KB)
  const int tid = threadIdx.x, lane = tid & 63, w = tid >> 6;
  const int r = lane & 15, hi = lane >> 4;
  const int i0 = blockIdx.x * 16;
  const int Kw = K >> 2;                // per-wave K slice
  const int kb0 = w * Kw;
  const int nt = Kw / 64;
  const int aR = hi;                    // A-load row within 4-row group
  const int aC = r * 4;                 // A-load f32 col (16B chunk)

  f32x4 ra[4][4];                       // 4-deep A tile rotation (64 VGPR)
  bf16x8 rb[4][8];                      // 4-deep B fragment sets (128 VGPR)
  f32x4 acc[4] = {};

  auto loadA = [&](f32x4 (&dst)[4], int t) {
    const int k0 = kb0 + t * 64;
#pragma unroll
    for (int s = 0; s < 4; ++s)
      dst[s] = __builtin_nontemporal_load(
          reinterpret_cast<const f32x4*>(&A[(size_t)(i0 + 4 * s + aR) * K + k0 + aC]));
  };
  auto loadB = [&](bf16x8 (&dst)[8], int t) {
    const int k0 = kb0 + t * 64;
#pragma unroll
    for (int n = 0; n < 4; ++n)
#pragma unroll
      for (int kk = 0; kk < 2; ++kk)
        dst[n * 2 + kk] = *reinterpret_cast<const bf16x8*>(
            &Bt[(size_t)(n * 16 + r) * K + k0 + kk * 32 + hi * 8]);
  };
  auto writeA = [&](int buf, const f32x4 (&src)[4]) {
    char* base = (char*)&As[w][buf][0];
#pragma unroll
    for (int s = 0; s < 4; ++s) {
      const int R = 4 * s + aR;
      bf16x4 o;
      o[0] = (bf16)src[s][0]; o[1] = (bf16)src[s][1];
      o[2] = (bf16)src[s][2]; o[3] = (bf16)src[s][3];
      *reinterpret_cast<bf16x4*>(base + R * 128 + ((aC * 2) ^ ((R & 7) << 4))) = o;
    }
  };
  auto compute = [&](int buf, const bf16x8 (&rbv)[8]) {
    const char* base = (const char*)&As[w][buf][0];
#pragma unroll
    for (int kk = 0; kk < 2; ++kk) {
      const bf16x8 fa = *reinterpret_cast<const bf16x8*>(
          base + r * 128 + ((kk * 64 + hi * 16) ^ ((r & 7) << 4)));
#pragma unroll
      for (int n = 0; n < 4; ++n)
        acc[n] = MFMA16(fa, rbv[n * 2 + kk], acc[n]);
    }
  };

  // prologue: A tiles 0..3 in regs, B tiles 0..2 in regs, A(0) into LDS buf0
  loadA(ra[0], 0);
  if (nt > 1) loadA(ra[1], 1);
  if (nt > 2) loadA(ra[2], 2);
  if (nt > 3) loadA(ra[3], 3);
  loadB(rb[0], 0);
  if (nt > 1) loadB(rb[1], 1);
  if (nt > 2) loadB(rb[2], 2);
  writeA(0, ra[0]);

  for (int tb = 0; tb < nt; tb += 4) {   // all slot indices compile-time
#pragma unroll
    for (int u = 0; u < 4; ++u) {
      const int t = tb + u;
      if (t >= nt) continue;
      if (t + 3 < nt) loadB(rb[(u + 3) & 3], t + 3);   // B 3 ahead
      if (t + 4 < nt) loadA(ra[u & 3], t + 4);         // A 4 ahead
      if (t + 1 < nt) writeA((u + 1) & 1, ra[(u + 1) & 3]);
      compute(u & 1, rb[u & 3]);
    }
  }

  // ---- cross-wave K-reduction + epilogue ----
  // C/D layout (m89-verified): col = lane&15, row = (lane>>4)*4 + reg
#pragma unroll
  for (int n = 0; n < 4; ++n)
#pragma unroll
    for (int g = 0; g < 4; ++g)
      Hred[w][hi * 4 + g][n * 16 + r] = acc[n][g];
  __syncthreads();
  {
    const int row = tid >> 4, c4 = (tid & 15) * 4;
    float4 s = {0.f, 0.f, 0.f, 0.f};
#pragma unroll
    for (int q = 0; q < 4; ++q) {
      const float4 v = *reinterpret_cast<const float4*>(&Hred[q][row][c4]);
      s.x += v.x; s.y += v.y; s.z += v.z; s.w += v.w;
    }
    if (EPI == 1) {
      s.x = fmaxf(s.x, 0.f); s.y = fmaxf(s.y, 0.f);
      s.z = fmaxf(s.z, 0.f); s.w = fmaxf(s.w, 0.f);
    }
    *reinterpret_cast<float4*>(&Ht[row][c4]) = s;
  }
  __syncthreads();

  if constexpr (EPI <= 1) {
    // transpose-store: outT[j][i0..i0+16], 256 threads (caching: re-read later)
    const int j = tid >> 2, iq = tid & 3;
    bf16x4 o;
#pragma unroll
    for (int e = 0; e < 4; ++e) o[e] = (bf16)Ht[iq * 4 + e][j];
    *reinterpret_cast<bf16x4*>(&outT[(size_t)j * N + i0 + iq * 4]) = o;
  } else {
    // second MFMA: [16][128] = Ht(16x64) @ W23; wave w does q-blocks 2w,2w+1
    f32x4 a2[2] = {};
#pragma unroll
    for (int kk = 0; kk < 2; ++kk) {
      const float4 t0 = *reinterpret_cast<const float4*>(&Ht[r][kk * 32 + hi * 8]);
      const float4 t1 = *reinterpret_cast<const float4*>(&Ht[r][kk * 32 + hi * 8 + 4]);
      bf16x8 fa;
      fa[0] = (bf16)t0.x; fa[1] = (bf16)t0.y; fa[2] = (bf16)t0.z; fa[3] = (bf16)t0.w;
      fa[4] = (bf16)t1.x; fa[5] = (bf16)t1.y; fa[6] = (bf16)t1.z; fa[7] = (bf16)t1.w;
#pragma unroll
      for (int j = 0; j < 2; ++j) {
        const int q = w * 2 + j;
        const bf16x8 fw = *reinterpret_cast<const bf16x8*>(
            &W23T[(size_t)(q * 16 + r) * 64 + kk * 32 + hi * 8]);
        a2[j] = MFMA16(fa, fw, a2[j]);
      }
    }
#pragma unroll
    for (int j = 0; j < 2; ++j) {
      const int q = w * 2 + j;
      float* dst = (q < 4) ? mu : lv;
      const int cc = (q & 3) * 16 + r;
#pragma unroll
      for (int g = 0; g < 4; ++g)
        dst[(size_t)(i0 + hi * 4 + g) * HID + cc] = a2[j][g];
    }
  }
}

// W1 -> W1T [64][256] bf16 ; W2,W3 -> W23T [128][64] bf16 (single dispatch)
__global__ void prep_weights(const float* __restrict__ W1, const float* __restrict__ W2,
                             const float* __restrict__ W3, bf16* __restrict__ W1T,
                             bf16* __restrict__ W23T) {
  const int idx = blockIdx.x * 256 + threadIdx.x;  // 96 blocks = 24576
  if (idx < 16384) {
    const int j = idx >> 8, k = idx & 255;
    W1T[idx] = (bf16)W1[k * HID + j];
  } else {
    const int g = idx - 16384;                      // 8192
    const int j = g >> 6, c = g & 63;
    W23T[g] = (bf16)(j < 64 ? W2[c * HID + j] : W3[c * HID + (j - 64)]);
  }
}

// recon[i][j] = dot(mu[i,:], mu[j,:]) ; K=64, write-bound. Caching stores
// (R23: nontemporal stores regressed).
constexpr int LDT = 72;
__global__ __launch_bounds__(256) void recon_mm(const float* __restrict__ mu,
                                                float* __restrict__ out) {
  __shared__ alignas(16) char pool[128 * LDT * 2 * 2];  // 36864 B: Am|Bm, then Ct
  bf16* Am = (bf16*)pool;                                // [128][72]
  bf16* Bm = (bf16*)(pool + 128 * LDT * 2);              // [128][72]
  float* Ct = (float*)pool;                              // [64][132] = 33792 B
  const int tid = threadIdx.x, lane = tid & 63, wave = tid >> 6;
  const int i0 = blockIdx.x * 128, j0 = blockIdx.y * 128;
  {
    const int rr = tid >> 4, c4 = tid & 15;
#pragma unroll
    for (int s = 0; s < 8; ++s) {
      const int row = rr + s * 16;
      const float4 v = *reinterpret_cast<const float4*>(&mu[(size_t)(i0 + row) * HID + c4 * 4]);
      bf16x4 o;
      o[0] = (bf16)v.x; o[1] = (bf16)v.y; o[2] = (bf16)v.z; o[3] = (bf16)v.w;
      *reinterpret_cast<bf16x4*>(&Am[row * LDT + c4 * 4]) = o;
      const float4 u = *reinterpret_cast<const float4*>(&mu[(size_t)(j0 + row) * HID + c4 * 4]);
      bf16x4 p;
      p[0] = (bf16)u.x; p[1] = (bf16)u.y; p[2] = (bf16)u.z; p[3] = (bf16)u.w;
      *reinterpret_cast<bf16x4*>(&Bm[row * LDT + c4 * 4]) = p;
    }
  }
  __syncthreads();
  f32x4 acc[2][8] = {};
  const int rA = wave * 32 + (lane & 15);
#pragma unroll
  for (int kk = 0; kk < 2; ++kk) {
    const int kb = kk * 32 + ((lane >> 4) << 3);
    const bf16x8 a0 = *reinterpret_cast<const bf16x8*>(&Am[rA * LDT + kb]);
    const bf16x8 a1 = *reinterpret_cast<const bf16x8*>(&Am[(rA + 16) * LDT + kb]);
#pragma unroll
    for (int n = 0; n < 8; ++n) {
      const bf16x8 b = *reinterpret_cast<const bf16x8*>(&Bm[(n * 16 + (lane & 15)) * LDT + kb]);
      acc[0][n] = MFMA16(a0, b, acc[0][n]);
      acc[1][n] = MFMA16(a1, b, acc[1][n]);
    }
  }
  const int r4 = (lane >> 4) << 2, c = lane & 15;
#pragma unroll
  for (int h = 0; h < 2; ++h) {
    __syncthreads();
    if ((wave >> 1) == h) {
      const int rbase = (wave & 1) * 32;
#pragma unroll
      for (int m = 0; m < 2; ++m)
#pragma unroll
        for (int n = 0; n < 8; ++n)
#pragma unroll
          for (int g = 0; g < 4; ++g)
            Ct[(rbase + m * 16 + r4 + g) * 132 + n * 16 + c] = acc[m][n][g];
    }
    __syncthreads();
#pragma unroll
    for (int s = 0; s < 8; ++s) {
      const int idx = tid + s * 256;       // 2048 float4 chunks
      const int row = idx >> 5, q = idx & 31;
      const float4 v = *reinterpret_cast<const float4*>(&Ct[row * 132 + q * 4]);
      *reinterpret_cast<float4*>(&out[(size_t)(i0 + h * 64 + row) * N + j0 + q * 4]) = v;
    }
  }
}

extern "C" void kernel_launch(void* const* d_in, const int* in_sizes, int n_in, void* d_out,
                              int out_size, void* d_ws, size_t ws_size, hipStream_t stream) {
  const float* x   = (const float*)d_in[0];
  const float* adj = (const float*)d_in[1];
  const float* W1  = (const float*)d_in[2];
  const float* W2  = (const float*)d_in[3];
  const float* W3  = (const float*)d_in[4];

  float* out    = (float*)d_out;
  float* recon  = out;                          // [8192][8192] 256 MiB
  float* mu_out = out + (size_t)N * N;          // outside recon region
  float* lv_out = mu_out + (size_t)N * HID;

  // Scratch inside recon region (first ~3 MiB); all dead before recon_mm runs.
  char* scr   = (char*)d_out;
  bf16* S1T   = (bf16*)(scr + 0);               // [64][8192]  1 MB
  bf16* h1T   = (bf16*)(scr + (1u << 20));      // [64][8192]  1 MB
  bf16* W1T   = (bf16*)(scr + (2u << 20));      // [64][256]   32 KB
  bf16* W23T  = (bf16*)(scr + (2u << 20) + 65536);  // [128][64] 16 KB

  prep_weights<<<96, 256, 0, stream>>>(W1, W2, W3, W1T, W23T);
  // S1T = (x @ W1)^T   (nontemporal x-stream)
  gcn_pass<0><<<512, 256, 0, stream>>>(x, 256, W1T, S1T, nullptr, nullptr, nullptr);
  // h1T = relu(adj @ s1)^T   (nontemporal A-stream)
  gcn_pass<1><<<512, 256, 0, stream>>>(adj, N, S1T, h1T, nullptr, nullptr, nullptr);
  // mu, lv = (adj @ h1) @ {W2,W3}
  gcn_pass<2><<<512, 256, 0, stream>>>(adj, N, h1T, nullptr, W23T, mu_out, lv_out);
  // recon = mu @ mu^T  (caching stores)
  recon_mm<<<dim3(64, 64), 256, 0, stream>>>(mu_out, recon);
}